// Round 1
// baseline (3176.063 us; speedup 1.0000x reference)
//
#include <hip/hip_runtime.h>
#include <stdint.h>

#define T_SEQ 256
#define NB    8
#define EMB   512
#define HID   1024
#define NOUT  32000

typedef float  f32x4  __attribute__((ext_vector_type(4)));
typedef __bf16 bf16x8 __attribute__((ext_vector_type(8)));

#define AS1 __attribute__((address_space(1)))
#define AS3 __attribute__((address_space(3)))

__device__ __forceinline__ unsigned short f2bf(float f) {
    uint32_t u = __builtin_bit_cast(uint32_t, f);
    u += 0x7FFFu + ((u >> 16) & 1u);   // RNE
    return (unsigned short)(u >> 16);
}

// ---------------- W_fc fp32 -> bf16 ----------------
__global__ void k_convert_wfc(const float* __restrict__ src, unsigned short* __restrict__ dst) {
    int i = blockIdx.x * blockDim.x + threadIdx.x;
    const f32x4* s4 = (const f32x4*)src;
    int n4 = NOUT * HID / 4;
    int stride = gridDim.x * blockDim.x;
    for (int idx = i; idx < n4; idx += stride) {
        f32x4 v = s4[idx];
        uint2 o;
        o.x = (uint32_t)f2bf(v.x) | ((uint32_t)f2bf(v.y) << 16);
        o.y = (uint32_t)f2bf(v.z) | ((uint32_t)f2bf(v.w) << 16);
        ((uint2*)dst)[idx] = o;
    }
}

// ---------------- embed gather + xproj = emb @ W_ih^T + b_ih (fp32) ----------------
// C[m][h], m = t*8+b, tiles 64x64, K=512
__global__ __launch_bounds__(256) void k_xproj(
        const int* __restrict__ inputs, const float* __restrict__ embed,
        const float* __restrict__ W_ih, const float* __restrict__ b_ih,
        float* __restrict__ xproj) {
    __shared__ float As[64][33];
    __shared__ float Bs[64][33];
    __shared__ int   idx_s[64];
    const int tid = threadIdx.x;
    const int bm = blockIdx.y, bn = blockIdx.x;
    if (tid < 64) {
        int m = bm * 64 + tid;
        idx_s[tid] = inputs[(m & 7) * T_SEQ + (m >> 3)];
    }
    __syncthreads();
    const int ty = tid >> 4, tx = tid & 15;
    const int lr = tid >> 2, lc = (tid & 3) * 8;
    float acc[4][4] = {};
    for (int kk = 0; kk < EMB; kk += 32) {
        __syncthreads();
        const float* arow = embed + (size_t)idx_s[lr] * EMB + kk + lc;
        f32x4 a0 = *(const f32x4*)arow;
        f32x4 a1 = *(const f32x4*)(arow + 4);
        const float* brow = W_ih + (size_t)(bn * 64 + lr) * EMB + kk + lc;
        f32x4 b0 = *(const f32x4*)brow;
        f32x4 b1 = *(const f32x4*)(brow + 4);
#pragma unroll
        for (int u = 0; u < 4; ++u) {
            As[lr][lc + u] = a0[u]; As[lr][lc + 4 + u] = a1[u];
            Bs[lr][lc + u] = b0[u]; Bs[lr][lc + 4 + u] = b1[u];
        }
        __syncthreads();
#pragma unroll
        for (int k = 0; k < 32; ++k) {
            float av[4], bv[4];
#pragma unroll
            for (int i = 0; i < 4; ++i) av[i] = As[ty * 4 + i][k];
#pragma unroll
            for (int j = 0; j < 4; ++j) bv[j] = Bs[tx * 4 + j][k];
#pragma unroll
            for (int i = 0; i < 4; ++i)
#pragma unroll
                for (int j = 0; j < 4; ++j) acc[i][j] += av[i] * bv[j];
        }
    }
#pragma unroll
    for (int i = 0; i < 4; ++i) {
        int m = bm * 64 + ty * 4 + i;
#pragma unroll
        for (int j = 0; j < 4; ++j) {
            int n = bn * 64 + tx * 4 + j;
            xproj[(size_t)m * HID + n] = acc[i][j] + b_ih[n];
        }
    }
}

// ---------------- persistent recurrence: 64 blocks x 256 threads ----------------
// block owns 16 output cols; wave w owns 4 cols; lane ln covers k = ln + 64q.
// W slice in registers; h_prev staged to LDS [1024][12] fp32; LDS reduce.
#define RBLK 64
__global__ __launch_bounds__(256, 1) void k_rnn(
        const float* __restrict__ W_hh, const float* __restrict__ b_hh,
        const float* __restrict__ xproj, float* __restrict__ hbuf /* [2][1024][8] */,
        unsigned short* __restrict__ hs /* [2048][1024] bf16 */,
        unsigned int* __restrict__ ctr) {
    __shared__ float smem[12288];   // 48 KB: h_s [1024][12]; aliased reduce [4][64][36]
    const int tid = threadIdx.x;
    const int w   = tid >> 6;
    const int ln  = tid & 63;
    const int blk = blockIdx.x;
    const int col0 = blk * 16 + w * 4;

    // preload W_hh slice: wreg[q][c] = W_hh[col0+c][ln + 64q]
    float wreg[16][4];
#pragma unroll
    for (int q = 0; q < 16; ++q)
#pragma unroll
        for (int c = 0; c < 4; ++c)
            wreg[q][c] = W_hh[(size_t)(col0 + c) * HID + ln + 64 * q];

    for (int t = 0; t < T_SEQ; ++t) {
        // stage h_{t-1} -> LDS [k][12]
        if (t > 0) {
            const f32x4* hp4 = (const f32x4*)(hbuf + (size_t)((t + 1) & 1) * HID * NB);
#pragma unroll
            for (int j = 0; j < 8; ++j) {
                f32x4 v = hp4[tid * 8 + j];
                int k = tid * 4 + (j >> 1);
                int b = (j & 1) * 4;
                *(f32x4*)&smem[k * 12 + b] = v;
            }
        }
        __syncthreads();
        float acc[32];
#pragma unroll
        for (int i = 0; i < 32; ++i) acc[i] = 0.f;
        if (t > 0) {
#pragma unroll
            for (int q = 0; q < 16; ++q) {
                int k = ln + 64 * q;
                f32x4 h0 = *(const f32x4*)&smem[k * 12];
                f32x4 h1 = *(const f32x4*)&smem[k * 12 + 4];
#pragma unroll
                for (int c = 0; c < 4; ++c) {
                    float wv = wreg[q][c];
                    acc[c * 8 + 0] += wv * h0.x; acc[c * 8 + 1] += wv * h0.y;
                    acc[c * 8 + 2] += wv * h0.z; acc[c * 8 + 3] += wv * h0.w;
                    acc[c * 8 + 4] += wv * h1.x; acc[c * 8 + 5] += wv * h1.y;
                    acc[c * 8 + 6] += wv * h1.z; acc[c * 8 + 7] += wv * h1.w;
                }
            }
        }
        __syncthreads();                       // h_s reads done; alias smem for reduce
        float* red = &smem[w * 2304];          // [64][36]
#pragma unroll
        for (int i = 0; i < 32; i += 4) {
            f32x4 v = { acc[i], acc[i + 1], acc[i + 2], acc[i + 3] };
            *(f32x4*)&red[ln * 36 + i] = v;
        }
        __syncthreads();
        if (ln < 32) {
            float s0 = 0.f, s1 = 0.f;
#pragma unroll
            for (int r = 0; r < 64; r += 2) {
                s0 += red[r * 36 + ln];
                s1 += red[(r + 1) * 36 + ln];
            }
            float sum = s0 + s1;
            int c = ln >> 3, b = ln & 7;
            int col = col0 + c;
            int m = t * NB + b;
            float x = xproj[(size_t)m * HID + col] + sum + b_hh[col];
            float h = tanhf(x);
            hbuf[(size_t)(t & 1) * HID * NB + col * NB + b] = h;
            hs[(size_t)m * HID + col] = f2bf(h);
        }
        __threadfence();
        __syncthreads();
        if (tid == 0) {
            __hip_atomic_fetch_add(ctr, 1u, __ATOMIC_RELEASE, __HIP_MEMORY_SCOPE_AGENT);
            unsigned int target = (unsigned int)RBLK * (unsigned int)(t + 1);
            while (__hip_atomic_load(ctr, __ATOMIC_ACQUIRE, __HIP_MEMORY_SCOPE_AGENT) < target)
                __builtin_amdgcn_s_sleep(1);
        }
        __syncthreads();
    }
}

// ---------------- fc: C[m][n] = hs[m][:] . W_fc[n][:] + b_fc[n], bf16 MFMA ----------------
// 128x128 tile, BK=32, 4 waves (2x2 of 64x64), m97 structure.
__global__ void k_fc(const unsigned short* __restrict__ A,   // [2048][1024] bf16
                     const unsigned short* __restrict__ Bw,  // [32000][1024] bf16
                     const float* __restrict__ bias,
                     float* __restrict__ out) {              // [8][256][32000] f32
    __shared__ __align__(16) unsigned short As[128 * 32];
    __shared__ __align__(16) unsigned short Bs[128 * 32];
    const int tid = threadIdx.x;
    const int w = tid >> 6, ln = tid & 63;
    const int bm = blockIdx.y, bn = blockIdx.x;
    const int wm = (w >> 1) * 64, wn = (w & 1) * 64;
    const int srow = tid >> 2;
    const int scol = (tid & 3) * 8;
    const unsigned short* Ag = A  + (size_t)(bm * 128 + srow) * 1024 + scol;
    const unsigned short* Bg = Bw + (size_t)(bn * 128 + srow) * 1024 + scol;
    unsigned short* ldsA0 = As + w * 512;
    unsigned short* ldsA1 = As + 2048 + w * 512;
    unsigned short* ldsB0 = Bs + w * 512;
    unsigned short* ldsB1 = Bs + 2048 + w * 512;

    f32x4 acc[4][4] = {};
    const int fr = ln & 15;
    const int kq = (ln >> 4) * 8;

    for (int kk = 0; kk < 1024; kk += 32) {
        __syncthreads();
        __builtin_amdgcn_global_load_lds((const AS1 void*)(Ag + kk),             (AS3 void*)ldsA0, 16, 0, 0);
        __builtin_amdgcn_global_load_lds((const AS1 void*)(Ag + 64 * 1024 + kk), (AS3 void*)ldsA1, 16, 0, 0);
        __builtin_amdgcn_global_load_lds((const AS1 void*)(Bg + kk),             (AS3 void*)ldsB0, 16, 0, 0);
        __builtin_amdgcn_global_load_lds((const AS1 void*)(Bg + 64 * 1024 + kk), (AS3 void*)ldsB1, 16, 0, 0);
        __syncthreads();
        bf16x8 af[4], bf[4];
#pragma unroll
        for (int i = 0; i < 4; ++i)
            af[i] = *(const bf16x8*)&As[(wm + i * 16 + fr) * 32 + kq];
#pragma unroll
        for (int j = 0; j < 4; ++j)
            bf[j] = *(const bf16x8*)&Bs[(wn + j * 16 + fr) * 32 + kq];
#pragma unroll
        for (int i = 0; i < 4; ++i)
#pragma unroll
            for (int j = 0; j < 4; ++j)
                acc[i][j] = __builtin_amdgcn_mfma_f32_16x16x32_bf16(af[i], bf[j], acc[i][j], 0, 0, 0);
    }

    const int fq = ln >> 4;
#pragma unroll
    for (int i = 0; i < 4; ++i) {
#pragma unroll
        for (int j = 0; j < 4; ++j) {
            int n = bn * 128 + wn + j * 16 + fr;
            float bv = bias[n];
#pragma unroll
            for (int r = 0; r < 4; ++r) {
                int m = bm * 128 + wm + i * 16 + fq * 4 + r;
                int t = m >> 3, b = m & 7;
                out[(size_t)b * T_SEQ * NOUT + (size_t)t * NOUT + n] = acc[i][j][r] + bv;
            }
        }
    }
}

extern "C" void kernel_launch(void* const* d_in, const int* in_sizes, int n_in,
                              void* d_out, int out_size, void* d_ws, size_t ws_size,
                              hipStream_t stream) {
    const int*   inputs = (const int*)d_in[0];
    const float* embed  = (const float*)d_in[1];
    const float* W_ih   = (const float*)d_in[2];
    const float* W_hh   = (const float*)d_in[3];
    const float* b_ih   = (const float*)d_in[4];
    const float* b_hh   = (const float*)d_in[5];
    const float* W_fc   = (const float*)d_in[6];
    const float* b_fc   = (const float*)d_in[7];
    float* out = (float*)d_out;

    char* ws = (char*)d_ws;
    unsigned int*   ctr   = (unsigned int*)(ws);                       // 256 B
    float*          hbuf  = (float*)(ws + 256);                       // 2*1024*8*4 = 64 KB
    float*          xproj = (float*)(ws + 256 + 65536);               // 2048*1024*4 = 8 MB
    unsigned short* hs    = (unsigned short*)(ws + 256 + 65536 + 8388608);          // 4 MB
    unsigned short* wfcb  = (unsigned short*)(ws + 256 + 65536 + 8388608 + 4194304); // 64 MB

    hipMemsetAsync(ctr, 0, 256, stream);
    k_convert_wfc<<<2048, 256, 0, stream>>>(W_fc, wfcb);
    k_xproj<<<dim3(16, 32), 256, 0, stream>>>(inputs, embed, W_ih, b_ih, xproj);
    k_rnn<<<RBLK, 256, 0, stream>>>(W_hh, b_hh, xproj, hbuf, hs, ctr);
    k_fc<<<dim3(250, 16), 256, 0, stream>>>(hs, wfcb, b_fc, out);
}

// Round 2
// 1858.994 us; speedup vs baseline: 1.7085x; 1.7085x over previous
//
#include <hip/hip_runtime.h>
#include <stdint.h>

#define T_SEQ 256
#define NB    8
#define EMB   512
#define HID   1024
#define NOUT  32000

typedef float  f32x4  __attribute__((ext_vector_type(4)));
typedef __bf16 bf16x8 __attribute__((ext_vector_type(8)));

#define AS1 __attribute__((address_space(1)))
#define AS3 __attribute__((address_space(3)))

__device__ __forceinline__ unsigned short f2bf(float f) {
    uint32_t u = __builtin_bit_cast(uint32_t, f);
    u += 0x7FFFu + ((u >> 16) & 1u);   // RNE
    return (unsigned short)(u >> 16);
}

// ---------------- W_fc fp32 -> bf16 ----------------
__global__ void k_convert_wfc(const float* __restrict__ src, unsigned short* __restrict__ dst) {
    int i = blockIdx.x * blockDim.x + threadIdx.x;
    const f32x4* s4 = (const f32x4*)src;
    int n4 = NOUT * HID / 4;
    int stride = gridDim.x * blockDim.x;
    for (int idx = i; idx < n4; idx += stride) {
        f32x4 v = s4[idx];
        uint2 o;
        o.x = (uint32_t)f2bf(v.x) | ((uint32_t)f2bf(v.y) << 16);
        o.y = (uint32_t)f2bf(v.z) | ((uint32_t)f2bf(v.w) << 16);
        ((uint2*)dst)[idx] = o;
    }
}

// ---------------- embed gather + xproj = emb @ W_ih^T + b_ih (fp32) ----------------
__global__ __launch_bounds__(256) void k_xproj(
        const int* __restrict__ inputs, const float* __restrict__ embed,
        const float* __restrict__ W_ih, const float* __restrict__ b_ih,
        float* __restrict__ xproj) {
    __shared__ float As[64][33];
    __shared__ float Bs[64][33];
    __shared__ int   idx_s[64];
    const int tid = threadIdx.x;
    const int bm = blockIdx.y, bn = blockIdx.x;
    if (tid < 64) {
        int m = bm * 64 + tid;
        idx_s[tid] = inputs[(m & 7) * T_SEQ + (m >> 3)];
    }
    __syncthreads();
    const int ty = tid >> 4, tx = tid & 15;
    const int lr = tid >> 2, lc = (tid & 3) * 8;
    float acc[4][4] = {};
    for (int kk = 0; kk < EMB; kk += 32) {
        __syncthreads();
        const float* arow = embed + (size_t)idx_s[lr] * EMB + kk + lc;
        f32x4 a0 = *(const f32x4*)arow;
        f32x4 a1 = *(const f32x4*)(arow + 4);
        const float* brow = W_ih + (size_t)(bn * 64 + lr) * EMB + kk + lc;
        f32x4 b0 = *(const f32x4*)brow;
        f32x4 b1 = *(const f32x4*)(brow + 4);
#pragma unroll
        for (int u = 0; u < 4; ++u) {
            As[lr][lc + u] = a0[u]; As[lr][lc + 4 + u] = a1[u];
            Bs[lr][lc + u] = b0[u]; Bs[lr][lc + 4 + u] = b1[u];
        }
        __syncthreads();
#pragma unroll
        for (int k = 0; k < 32; ++k) {
            float av[4], bv[4];
#pragma unroll
            for (int i = 0; i < 4; ++i) av[i] = As[ty * 4 + i][k];
#pragma unroll
            for (int j = 0; j < 4; ++j) bv[j] = Bs[tx * 4 + j][k];
#pragma unroll
            for (int i = 0; i < 4; ++i)
#pragma unroll
                for (int j = 0; j < 4; ++j) acc[i][j] += av[i] * bv[j];
        }
    }
#pragma unroll
    for (int i = 0; i < 4; ++i) {
        int m = bm * 64 + ty * 4 + i;
#pragma unroll
        for (int j = 0; j < 4; ++j) {
            int n = bn * 64 + tx * 4 + j;
            xproj[(size_t)m * HID + n] = acc[i][j] + b_ih[n];
        }
    }
}

// ---------------- persistent recurrence: 64 blocks x 256 threads ----------------
// Manual coherence: h stores write-through (sc0 sc1) to the coherent point,
// per-block arrival slots (plain WT stores, no atomics), one-wave parallel
// slot poll with bypass loads. No threadfence, no buffer_wbl2/inv storms.
#define RBLK 64
__global__ __launch_bounds__(256, 1) void k_rnn(
        const float* __restrict__ W_hh, const float* __restrict__ b_hh,
        const float* __restrict__ xproj, float* __restrict__ hbuf /* [2][1024][8] */,
        unsigned short* __restrict__ hs /* [2048][1024] bf16 */,
        unsigned int* __restrict__ slots /* [64] */) {
    __shared__ float smem[12288];   // 48 KB: h_s [1024][12]; aliased reduce [4][64][36]
    const int tid = threadIdx.x;
    const int w   = tid >> 6;
    const int ln  = tid & 63;
    const int blk = blockIdx.x;
    const int col0 = blk * 16 + w * 4;

    // preload W_hh slice: wreg[q][c] = W_hh[col0+c][ln + 64q]
    float wreg[16][4];
#pragma unroll
    for (int q = 0; q < 16; ++q)
#pragma unroll
        for (int c = 0; c < 4; ++c)
            wreg[q][c] = W_hh[(size_t)(col0 + c) * HID + ln + 64 * q];

    for (int t = 0; t < T_SEQ; ++t) {
        // stage h_{t-1} -> LDS [k][12], reading fresh from coherent point
        if (t > 0) {
            const float* hp = hbuf + (size_t)((t + 1) & 1) * HID * NB + tid * 32;
            f32x4 r0, r1, r2, r3, r4, r5, r6, r7;
            asm volatile(
                "global_load_dwordx4 %0, %8, off sc0 sc1\n\t"
                "global_load_dwordx4 %1, %8, off offset:16 sc0 sc1\n\t"
                "global_load_dwordx4 %2, %8, off offset:32 sc0 sc1\n\t"
                "global_load_dwordx4 %3, %8, off offset:48 sc0 sc1\n\t"
                "global_load_dwordx4 %4, %8, off offset:64 sc0 sc1\n\t"
                "global_load_dwordx4 %5, %8, off offset:80 sc0 sc1\n\t"
                "global_load_dwordx4 %6, %8, off offset:96 sc0 sc1\n\t"
                "global_load_dwordx4 %7, %8, off offset:112 sc0 sc1\n\t"
                "s_waitcnt vmcnt(0)"
                : "=&v"(r0), "=&v"(r1), "=&v"(r2), "=&v"(r3),
                  "=&v"(r4), "=&v"(r5), "=&v"(r6), "=&v"(r7)
                : "v"(hp)
                : "memory");
            int kb = tid * 4;
            *(f32x4*)&smem[(kb + 0) * 12 + 0] = r0;
            *(f32x4*)&smem[(kb + 0) * 12 + 4] = r1;
            *(f32x4*)&smem[(kb + 1) * 12 + 0] = r2;
            *(f32x4*)&smem[(kb + 1) * 12 + 4] = r3;
            *(f32x4*)&smem[(kb + 2) * 12 + 0] = r4;
            *(f32x4*)&smem[(kb + 2) * 12 + 4] = r5;
            *(f32x4*)&smem[(kb + 3) * 12 + 0] = r6;
            *(f32x4*)&smem[(kb + 3) * 12 + 4] = r7;
        }
        __syncthreads();
        float acc[32];
#pragma unroll
        for (int i = 0; i < 32; ++i) acc[i] = 0.f;
        if (t > 0) {
#pragma unroll
            for (int q = 0; q < 16; ++q) {
                int k = ln + 64 * q;
                f32x4 h0 = *(const f32x4*)&smem[k * 12];
                f32x4 h1 = *(const f32x4*)&smem[k * 12 + 4];
#pragma unroll
                for (int c = 0; c < 4; ++c) {
                    float wv = wreg[q][c];
                    acc[c * 8 + 0] += wv * h0.x; acc[c * 8 + 1] += wv * h0.y;
                    acc[c * 8 + 2] += wv * h0.z; acc[c * 8 + 3] += wv * h0.w;
                    acc[c * 8 + 4] += wv * h1.x; acc[c * 8 + 5] += wv * h1.y;
                    acc[c * 8 + 6] += wv * h1.z; acc[c * 8 + 7] += wv * h1.w;
                }
            }
        }
        __syncthreads();                       // h_s reads done; alias smem for reduce
        float* red = &smem[w * 2304];          // [64][36]
#pragma unroll
        for (int i = 0; i < 32; i += 4) {
            f32x4 v = { acc[i], acc[i + 1], acc[i + 2], acc[i + 3] };
            *(f32x4*)&red[ln * 36 + i] = v;
        }
        __syncthreads();
        if (ln < 32) {
            float s0 = 0.f, s1 = 0.f;
#pragma unroll
            for (int r = 0; r < 64; r += 2) {
                s0 += red[r * 36 + ln];
                s1 += red[(r + 1) * 36 + ln];
            }
            float sum = s0 + s1;
            int c = ln >> 3, b = ln & 7;
            int col = col0 + c;
            int m = t * NB + b;
            float x = xproj[(size_t)m * HID + col] + sum + b_hh[col];
            float h = tanhf(x);
            // write-through store: device-visible once vmcnt retires
            float* haddr = hbuf + (size_t)(t & 1) * HID * NB + col * NB + b;
            asm volatile("global_store_dword %0, %1, off sc0 sc1"
                         :: "v"(haddr), "v"(h) : "memory");
            hs[(size_t)m * HID + col] = f2bf(h);
        }
        if (t < T_SEQ - 1) {
            // drain own h stores, then publish arrival, then wait for all 64
            asm volatile("s_waitcnt vmcnt(0)" ::: "memory");
            __syncthreads();
            if (tid == 0) {
                unsigned int tv = (unsigned int)(t + 1);
                const unsigned int* sp = slots + blk;
                asm volatile("global_store_dword %0, %1, off sc0 sc1"
                             :: "v"(sp), "v"(tv) : "memory");
            }
            if (w == 0) {
                const unsigned int* sp = slots + ln;
                unsigned int v;
                unsigned int target = (unsigned int)(t + 1);
                do {
                    asm volatile("global_load_dword %0, %1, off sc0 sc1\n\t"
                                 "s_waitcnt vmcnt(0)"
                                 : "=v"(v) : "v"(sp) : "memory");
                } while (!__all(v >= target));
            }
            __syncthreads();
        }
    }
}

// ---------------- fc: C[m][n] = hs[m][:] . W_fc[n][:] + b_fc[n], bf16 MFMA ----------------
__global__ void k_fc(const unsigned short* __restrict__ A,   // [2048][1024] bf16
                     const unsigned short* __restrict__ Bw,  // [32000][1024] bf16
                     const float* __restrict__ bias,
                     float* __restrict__ out) {              // [8][256][32000] f32
    __shared__ __align__(16) unsigned short As[128 * 32];
    __shared__ __align__(16) unsigned short Bs[128 * 32];
    const int tid = threadIdx.x;
    const int w = tid >> 6, ln = tid & 63;
    const int bm = blockIdx.y, bn = blockIdx.x;
    const int wm = (w >> 1) * 64, wn = (w & 1) * 64;
    const int srow = tid >> 2;
    const int scol = (tid & 3) * 8;
    const unsigned short* Ag = A  + (size_t)(bm * 128 + srow) * 1024 + scol;
    const unsigned short* Bg = Bw + (size_t)(bn * 128 + srow) * 1024 + scol;
    unsigned short* ldsA0 = As + w * 512;
    unsigned short* ldsA1 = As + 2048 + w * 512;
    unsigned short* ldsB0 = Bs + w * 512;
    unsigned short* ldsB1 = Bs + 2048 + w * 512;

    f32x4 acc[4][4] = {};
    const int fr = ln & 15;
    const int kq = (ln >> 4) * 8;

    for (int kk = 0; kk < 1024; kk += 32) {
        __syncthreads();
        __builtin_amdgcn_global_load_lds((const AS1 void*)(Ag + kk),             (AS3 void*)ldsA0, 16, 0, 0);
        __builtin_amdgcn_global_load_lds((const AS1 void*)(Ag + 64 * 1024 + kk), (AS3 void*)ldsA1, 16, 0, 0);
        __builtin_amdgcn_global_load_lds((const AS1 void*)(Bg + kk),             (AS3 void*)ldsB0, 16, 0, 0);
        __builtin_amdgcn_global_load_lds((const AS1 void*)(Bg + 64 * 1024 + kk), (AS3 void*)ldsB1, 16, 0, 0);
        __syncthreads();
        bf16x8 af[4], bf[4];
#pragma unroll
        for (int i = 0; i < 4; ++i)
            af[i] = *(const bf16x8*)&As[(wm + i * 16 + fr) * 32 + kq];
#pragma unroll
        for (int j = 0; j < 4; ++j)
            bf[j] = *(const bf16x8*)&Bs[(wn + j * 16 + fr) * 32 + kq];
#pragma unroll
        for (int i = 0; i < 4; ++i)
#pragma unroll
            for (int j = 0; j < 4; ++j)
                acc[i][j] = __builtin_amdgcn_mfma_f32_16x16x32_bf16(af[i], bf[j], acc[i][j], 0, 0, 0);
    }

    const int fq = ln >> 4;
#pragma unroll
    for (int i = 0; i < 4; ++i) {
#pragma unroll
        for (int j = 0; j < 4; ++j) {
            int n = bn * 128 + wn + j * 16 + fr;
            float bv = bias[n];
#pragma unroll
            for (int r = 0; r < 4; ++r) {
                int m = bm * 128 + wm + i * 16 + fq * 4 + r;
                int t = m >> 3, b = m & 7;
                out[(size_t)b * T_SEQ * NOUT + (size_t)t * NOUT + n] = acc[i][j][r] + bv;
            }
        }
    }
}

extern "C" void kernel_launch(void* const* d_in, const int* in_sizes, int n_in,
                              void* d_out, int out_size, void* d_ws, size_t ws_size,
                              hipStream_t stream) {
    const int*   inputs = (const int*)d_in[0];
    const float* embed  = (const float*)d_in[1];
    const float* W_ih   = (const float*)d_in[2];
    const float* W_hh   = (const float*)d_in[3];
    const float* b_ih   = (const float*)d_in[4];
    const float* b_hh   = (const float*)d_in[5];
    const float* W_fc   = (const float*)d_in[6];
    const float* b_fc   = (const float*)d_in[7];
    float* out = (float*)d_out;

    char* ws = (char*)d_ws;
    unsigned int*   slots = (unsigned int*)(ws);                       // 256 B (64 x u32)
    float*          hbuf  = (float*)(ws + 256);                        // 2*1024*8*4 = 64 KB
    float*          xproj = (float*)(ws + 256 + 65536);                // 2048*1024*4 = 8 MB
    unsigned short* hs    = (unsigned short*)(ws + 256 + 65536 + 8388608);           // 4 MB
    unsigned short* wfcb  = (unsigned short*)(ws + 256 + 65536 + 8388608 + 4194304); // 64 MB

    hipMemsetAsync(slots, 0, 256, stream);
    k_convert_wfc<<<2048, 256, 0, stream>>>(W_fc, wfcb);
    k_xproj<<<dim3(16, 32), 256, 0, stream>>>(inputs, embed, W_ih, b_ih, xproj);
    k_rnn<<<RBLK, 256, 0, stream>>>(W_hh, b_hh, xproj, hbuf, hs, slots);
    k_fc<<<dim3(250, 16), 256, 0, stream>>>(hs, wfcb, b_fc, out);
}

// Round 3
// 1446.512 us; speedup vs baseline: 2.1957x; 1.2852x over previous
//
#include <hip/hip_runtime.h>
#include <stdint.h>

#define T_SEQ 256
#define NB    8
#define EMB   512
#define HID   1024
#define NOUT  32000
#define RING  16

typedef float  f32x4  __attribute__((ext_vector_type(4)));
typedef __bf16 bf16x8 __attribute__((ext_vector_type(8)));

#define AS1 __attribute__((address_space(1)))
#define AS3 __attribute__((address_space(3)))

__device__ __forceinline__ unsigned short f2bf(float f) {
    uint32_t u = __builtin_bit_cast(uint32_t, f);
    u += 0x7FFFu + ((u >> 16) & 1u);   // RNE
    return (unsigned short)(u >> 16);
}

// ---------------- sentinel fill of the h ring (write-through) ----------------
__global__ void k_fill(float* __restrict__ p) {   // RING*1024*8 floats = 512 KB
    int i = blockIdx.x * blockDim.x + threadIdx.x;   // 128 blocks x 256 thr x 4 floats
    f32x4 v = { 2.0f, 2.0f, 2.0f, 2.0f };
    float* addr = p + (size_t)i * 4;
    asm volatile("global_store_dwordx4 %0, %1, off sc0 sc1"
                 :: "v"(addr), "v"(v) : "memory");
}

// ---------------- W_fc fp32 -> bf16 ----------------
__global__ void k_convert_wfc(const float* __restrict__ src, unsigned short* __restrict__ dst) {
    int i = blockIdx.x * blockDim.x + threadIdx.x;
    const f32x4* s4 = (const f32x4*)src;
    int n4 = NOUT * HID / 4;
    int stride = gridDim.x * blockDim.x;
    for (int idx = i; idx < n4; idx += stride) {
        f32x4 v = s4[idx];
        uint2 o;
        o.x = (uint32_t)f2bf(v.x) | ((uint32_t)f2bf(v.y) << 16);
        o.y = (uint32_t)f2bf(v.z) | ((uint32_t)f2bf(v.w) << 16);
        ((uint2*)dst)[idx] = o;
    }
}

// ---------------- embed gather + xproj = emb @ W_ih^T + b_ih (fp32) ----------------
__global__ __launch_bounds__(256) void k_xproj(
        const int* __restrict__ inputs, const float* __restrict__ embed,
        const float* __restrict__ W_ih, const float* __restrict__ b_ih,
        float* __restrict__ xproj) {
    __shared__ float As[64][33];
    __shared__ float Bs[64][33];
    __shared__ int   idx_s[64];
    const int tid = threadIdx.x;
    const int bm = blockIdx.y, bn = blockIdx.x;
    if (tid < 64) {
        int m = bm * 64 + tid;
        idx_s[tid] = inputs[(m & 7) * T_SEQ + (m >> 3)];
    }
    __syncthreads();
    const int ty = tid >> 4, tx = tid & 15;
    const int lr = tid >> 2, lc = (tid & 3) * 8;
    float acc[4][4] = {};
    for (int kk = 0; kk < EMB; kk += 32) {
        __syncthreads();
        const float* arow = embed + (size_t)idx_s[lr] * EMB + kk + lc;
        f32x4 a0 = *(const f32x4*)arow;
        f32x4 a1 = *(const f32x4*)(arow + 4);
        const float* brow = W_ih + (size_t)(bn * 64 + lr) * EMB + kk + lc;
        f32x4 b0 = *(const f32x4*)brow;
        f32x4 b1 = *(const f32x4*)(brow + 4);
#pragma unroll
        for (int u = 0; u < 4; ++u) {
            As[lr][lc + u] = a0[u]; As[lr][lc + 4 + u] = a1[u];
            Bs[lr][lc + u] = b0[u]; Bs[lr][lc + 4 + u] = b1[u];
        }
        __syncthreads();
#pragma unroll
        for (int k = 0; k < 32; ++k) {
            float av[4], bv[4];
#pragma unroll
            for (int i = 0; i < 4; ++i) av[i] = As[ty * 4 + i][k];
#pragma unroll
            for (int j = 0; j < 4; ++j) bv[j] = Bs[tx * 4 + j][k];
#pragma unroll
            for (int i = 0; i < 4; ++i)
#pragma unroll
                for (int j = 0; j < 4; ++j) acc[i][j] += av[i] * bv[j];
        }
    }
#pragma unroll
    for (int i = 0; i < 4; ++i) {
        int m = bm * 64 + ty * 4 + i;
#pragma unroll
        for (int j = 0; j < 4; ++j) {
            int n = bn * 64 + tx * 4 + j;
            xproj[(size_t)m * HID + n] = acc[i][j] + b_ih[n];
        }
    }
}

// ---------------- persistent recurrence: 64 blocks x 256 threads ----------------
// Sentinel-poll dataflow sync: no flags, no global barrier. h ring slot t%16 is
// sentinel-prefilled (2.0f, unreachable for tanh); producers store write-through
// and never wait; consumers poll their own chunk until all values != sentinel.
// Each block sentinel-refills its own 16 columns of slot (t+13)%16 each step
// (skew <=1 step makes this race-free; see round-3 derivation).
#define RBLK 64
__global__ __launch_bounds__(256, 1) void k_rnn(
        const float* __restrict__ W_hh, const float* __restrict__ b_hh,
        const float* __restrict__ xproj,
        float* __restrict__ hseq /* [RING][1024][8] */,
        unsigned short* __restrict__ hs /* [2048][1024] bf16 */) {
    __shared__ float smem[12288];   // 48 KB: h_s [1024][12]; aliased reduce [4][64][36]
    const int tid = threadIdx.x;
    const int w   = tid >> 6;
    const int ln  = tid & 63;
    const int blk = blockIdx.x;
    const int col0 = blk * 16 + w * 4;

    // preload W_hh slice: wreg[q][c] = W_hh[col0+c][ln + 64q]
    float wreg[16][4];
#pragma unroll
    for (int q = 0; q < 16; ++q)
#pragma unroll
        for (int c = 0; c < 4; ++c)
            wreg[q][c] = W_hh[(size_t)(col0 + c) * HID + ln + 64 * q];

    for (int t = 0; t < T_SEQ; ++t) {
        // poll + stage h_{t-1} -> LDS [k][12]; the poll load IS the h load
        if (t > 0) {
            const float* hp = hseq + (size_t)((t - 1) & (RING - 1)) * HID * NB + tid * 32;
            f32x4 r0, r1, r2, r3, r4, r5, r6, r7;
            bool ok;
            do {
                asm volatile(
                    "global_load_dwordx4 %0, %8, off sc0 sc1\n\t"
                    "global_load_dwordx4 %1, %8, off offset:16 sc0 sc1\n\t"
                    "global_load_dwordx4 %2, %8, off offset:32 sc0 sc1\n\t"
                    "global_load_dwordx4 %3, %8, off offset:48 sc0 sc1\n\t"
                    "global_load_dwordx4 %4, %8, off offset:64 sc0 sc1\n\t"
                    "global_load_dwordx4 %5, %8, off offset:80 sc0 sc1\n\t"
                    "global_load_dwordx4 %6, %8, off offset:96 sc0 sc1\n\t"
                    "global_load_dwordx4 %7, %8, off offset:112 sc0 sc1\n\t"
                    "s_waitcnt vmcnt(0)"
                    : "=&v"(r0), "=&v"(r1), "=&v"(r2), "=&v"(r3),
                      "=&v"(r4), "=&v"(r5), "=&v"(r6), "=&v"(r7)
                    : "v"(hp)
                    : "memory");
                ok =  (r0.x != 2.0f) & (r0.y != 2.0f) & (r0.z != 2.0f) & (r0.w != 2.0f)
                    & (r1.x != 2.0f) & (r1.y != 2.0f) & (r1.z != 2.0f) & (r1.w != 2.0f)
                    & (r2.x != 2.0f) & (r2.y != 2.0f) & (r2.z != 2.0f) & (r2.w != 2.0f)
                    & (r3.x != 2.0f) & (r3.y != 2.0f) & (r3.z != 2.0f) & (r3.w != 2.0f)
                    & (r4.x != 2.0f) & (r4.y != 2.0f) & (r4.z != 2.0f) & (r4.w != 2.0f)
                    & (r5.x != 2.0f) & (r5.y != 2.0f) & (r5.z != 2.0f) & (r5.w != 2.0f)
                    & (r6.x != 2.0f) & (r6.y != 2.0f) & (r6.z != 2.0f) & (r6.w != 2.0f)
                    & (r7.x != 2.0f) & (r7.y != 2.0f) & (r7.z != 2.0f) & (r7.w != 2.0f);
            } while (!ok);
            int kb = tid * 4;
            *(f32x4*)&smem[(kb + 0) * 12 + 0] = r0;
            *(f32x4*)&smem[(kb + 0) * 12 + 4] = r1;
            *(f32x4*)&smem[(kb + 1) * 12 + 0] = r2;
            *(f32x4*)&smem[(kb + 1) * 12 + 4] = r3;
            *(f32x4*)&smem[(kb + 2) * 12 + 0] = r4;
            *(f32x4*)&smem[(kb + 2) * 12 + 4] = r5;
            *(f32x4*)&smem[(kb + 3) * 12 + 0] = r6;
            *(f32x4*)&smem[(kb + 3) * 12 + 4] = r7;
        }
        __syncthreads();
        float acc[32];
#pragma unroll
        for (int i = 0; i < 32; ++i) acc[i] = 0.f;
        if (t > 0) {
#pragma unroll
            for (int q = 0; q < 16; ++q) {
                int k = ln + 64 * q;
                f32x4 h0 = *(const f32x4*)&smem[k * 12];
                f32x4 h1 = *(const f32x4*)&smem[k * 12 + 4];
#pragma unroll
                for (int c = 0; c < 4; ++c) {
                    float wv = wreg[q][c];
                    acc[c * 8 + 0] += wv * h0.x; acc[c * 8 + 1] += wv * h0.y;
                    acc[c * 8 + 2] += wv * h0.z; acc[c * 8 + 3] += wv * h0.w;
                    acc[c * 8 + 4] += wv * h1.x; acc[c * 8 + 5] += wv * h1.y;
                    acc[c * 8 + 6] += wv * h1.z; acc[c * 8 + 7] += wv * h1.w;
                }
            }
        }
        __syncthreads();                       // h_s reads done; alias smem for reduce
        float* red = &smem[w * 2304];          // [64][36]
#pragma unroll
        for (int i = 0; i < 32; i += 4) {
            f32x4 v = { acc[i], acc[i + 1], acc[i + 2], acc[i + 3] };
            *(f32x4*)&red[ln * 36 + i] = v;
        }
        __syncthreads();
        if (ln < 32) {
            float s0 = 0.f, s1 = 0.f;
#pragma unroll
            for (int r = 0; r < 64; r += 2) {
                s0 += red[r * 36 + ln];
                s1 += red[(r + 1) * 36 + ln];
            }
            float sum = s0 + s1;
            int c = ln >> 3, b = ln & 7;
            int col = col0 + c;
            int m = t * NB + b;
            float x = xproj[(size_t)m * HID + col] + sum + b_hh[col];
            float h = tanhf(x);
            // publish h: write-through, no wait — consumers' polls gate on it
            float* haddr = hseq + (size_t)(t & (RING - 1)) * HID * NB + col * NB + b;
            asm volatile("global_store_dword %0, %1, off sc0 sc1"
                         :: "v"(haddr), "v"(h) : "memory");
            hs[(size_t)m * HID + col] = f2bf(h);
            // sentinel-refill my columns of the slot that will hold h_{t+13}
            float* faddr = hseq + (size_t)((t + RING - 3) & (RING - 1)) * HID * NB + col * NB + b;
            float sen = 2.0f;
            asm volatile("global_store_dword %0, %1, off sc0 sc1"
                         :: "v"(faddr), "v"(sen) : "memory");
        }
        __syncthreads();   // protect smem (red) from next step's staging writes
    }
}

// ---------------- fc: C[m][n] = hs[m][:] . W_fc[n][:] + b_fc[n], bf16 MFMA ----------------
// grid dim3(16,250): bm fast -> the 16 consumers of each B-tile dispatch adjacently
__global__ void k_fc(const unsigned short* __restrict__ A,   // [2048][1024] bf16
                     const unsigned short* __restrict__ Bw,  // [32000][1024] bf16
                     const float* __restrict__ bias,
                     float* __restrict__ out) {              // [8][256][32000] f32
    __shared__ __align__(16) unsigned short As[128 * 32];
    __shared__ __align__(16) unsigned short Bs[128 * 32];
    const int tid = threadIdx.x;
    const int w = tid >> 6, ln = tid & 63;
    const int bm = blockIdx.x, bn = blockIdx.y;
    const int wm = (w >> 1) * 64, wn = (w & 1) * 64;
    const int srow = tid >> 2;
    const int scol = (tid & 3) * 8;
    const unsigned short* Ag = A  + (size_t)(bm * 128 + srow) * 1024 + scol;
    const unsigned short* Bg = Bw + (size_t)(bn * 128 + srow) * 1024 + scol;
    unsigned short* ldsA0 = As + w * 512;
    unsigned short* ldsA1 = As + 2048 + w * 512;
    unsigned short* ldsB0 = Bs + w * 512;
    unsigned short* ldsB1 = Bs + 2048 + w * 512;

    f32x4 acc[4][4] = {};
    const int fr = ln & 15;
    const int kq = (ln >> 4) * 8;

    for (int kk = 0; kk < 1024; kk += 32) {
        __syncthreads();
        __builtin_amdgcn_global_load_lds((const AS1 void*)(Ag + kk),             (AS3 void*)ldsA0, 16, 0, 0);
        __builtin_amdgcn_global_load_lds((const AS1 void*)(Ag + 64 * 1024 + kk), (AS3 void*)ldsA1, 16, 0, 0);
        __builtin_amdgcn_global_load_lds((const AS1 void*)(Bg + kk),             (AS3 void*)ldsB0, 16, 0, 0);
        __builtin_amdgcn_global_load_lds((const AS1 void*)(Bg + 64 * 1024 + kk), (AS3 void*)ldsB1, 16, 0, 0);
        __syncthreads();
        bf16x8 af[4], bf[4];
#pragma unroll
        for (int i = 0; i < 4; ++i)
            af[i] = *(const bf16x8*)&As[(wm + i * 16 + fr) * 32 + kq];
#pragma unroll
        for (int j = 0; j < 4; ++j)
            bf[j] = *(const bf16x8*)&Bs[(wn + j * 16 + fr) * 32 + kq];
#pragma unroll
        for (int i = 0; i < 4; ++i)
#pragma unroll
            for (int j = 0; j < 4; ++j)
                acc[i][j] = __builtin_amdgcn_mfma_f32_16x16x32_bf16(af[i], bf[j], acc[i][j], 0, 0, 0);
    }

    const int fq = ln >> 4;
#pragma unroll
    for (int i = 0; i < 4; ++i) {
#pragma unroll
        for (int j = 0; j < 4; ++j) {
            int n = bn * 128 + wn + j * 16 + fr;
            float bv = bias[n];
#pragma unroll
            for (int r = 0; r < 4; ++r) {
                int m = bm * 128 + wm + i * 16 + fq * 4 + r;
                int t = m >> 3, b = m & 7;
                out[(size_t)b * T_SEQ * NOUT + (size_t)t * NOUT + n] = acc[i][j][r] + bv;
            }
        }
    }
}

extern "C" void kernel_launch(void* const* d_in, const int* in_sizes, int n_in,
                              void* d_out, int out_size, void* d_ws, size_t ws_size,
                              hipStream_t stream) {
    const int*   inputs = (const int*)d_in[0];
    const float* embed  = (const float*)d_in[1];
    const float* W_ih   = (const float*)d_in[2];
    const float* W_hh   = (const float*)d_in[3];
    const float* b_ih   = (const float*)d_in[4];
    const float* b_hh   = (const float*)d_in[5];
    const float* W_fc   = (const float*)d_in[6];
    const float* b_fc   = (const float*)d_in[7];
    float* out = (float*)d_out;

    char* ws = (char*)d_ws;
    float*          hseq  = (float*)(ws);                               // RING*1024*8*4 = 512 KB
    float*          xproj = (float*)(ws + 524288);                      // 2048*1024*4 = 8 MB
    unsigned short* hs    = (unsigned short*)(ws + 524288 + 8388608);   // 4 MB
    unsigned short* wfcb  = (unsigned short*)(ws + 524288 + 8388608 + 4194304); // 64 MB

    k_fill<<<128, 256, 0, stream>>>(hseq);
    k_convert_wfc<<<2048, 256, 0, stream>>>(W_fc, wfcb);
    k_xproj<<<dim3(16, 32), 256, 0, stream>>>(inputs, embed, W_ih, b_ih, xproj);
    k_rnn<<<RBLK, 256, 0, stream>>>(W_hh, b_hh, xproj, hseq, hs);
    k_fc<<<dim3(16, 250), 256, 0, stream>>>(hs, wfcb, b_fc, out);
}

// Round 4
// 1397.433 us; speedup vs baseline: 2.2728x; 1.0351x over previous
//
#include <hip/hip_runtime.h>
#include <stdint.h>

#define T_SEQ 256
#define NB    8
#define EMB   512
#define HID   1024
#define NOUT  32000
#define RING  16
#define SEN   0x40004000u

typedef float    f32x4  __attribute__((ext_vector_type(4)));
typedef unsigned int u32x4 __attribute__((ext_vector_type(4)));
typedef __bf16   bf16x8 __attribute__((ext_vector_type(8)));

#define AS1 __attribute__((address_space(1)))
#define AS3 __attribute__((address_space(3)))

__device__ __forceinline__ uint32_t f2bf(float f) {
    uint32_t u = __builtin_bit_cast(uint32_t, f);
    u += 0x7FFFu + ((u >> 16) & 1u);   // RNE
    return (u >> 16);
}

// pack hi16 halves of (a=j0..3, b=j4..7) into a bf16x8 fragment
__device__ __forceinline__ bf16x8 mk_hi(u32x4 a, u32x4 b) {
    u32x4 r;
    r.x = __builtin_amdgcn_perm(a.y, a.x, 0x07060302u);
    r.y = __builtin_amdgcn_perm(a.w, a.z, 0x07060302u);
    r.z = __builtin_amdgcn_perm(b.y, b.x, 0x07060302u);
    r.w = __builtin_amdgcn_perm(b.w, b.z, 0x07060302u);
    return __builtin_bit_cast(bf16x8, r);
}
__device__ __forceinline__ bf16x8 mk_lo(u32x4 a, u32x4 b) {
    u32x4 r;
    r.x = __builtin_amdgcn_perm(a.y, a.x, 0x05040100u);
    r.y = __builtin_amdgcn_perm(a.w, a.z, 0x05040100u);
    r.z = __builtin_amdgcn_perm(b.y, b.x, 0x05040100u);
    r.w = __builtin_amdgcn_perm(b.w, b.z, 0x05040100u);
    return __builtin_bit_cast(bf16x8, r);
}

// ---------------- sentinel fill of the packed-h ring ----------------
__global__ void k_fill(unsigned int* __restrict__ p) {  // RING*8*1024 u32 = 512 KB
    int i = blockIdx.x * blockDim.x + threadIdx.x;      // 128 x 256 x 4
    u32x4 v = { SEN, SEN, SEN, SEN };
    unsigned int* addr = p + (size_t)i * 4;
    asm volatile("global_store_dwordx4 %0, %1, off sc0 sc1"
                 :: "v"(addr), "v"(v) : "memory");
}

// ---------------- W_fc fp32 -> bf16 ----------------
__global__ void k_convert_wfc(const float* __restrict__ src, unsigned short* __restrict__ dst) {
    int i = blockIdx.x * blockDim.x + threadIdx.x;
    const f32x4* s4 = (const f32x4*)src;
    int n4 = NOUT * HID / 4;
    int stride = gridDim.x * blockDim.x;
    for (int idx = i; idx < n4; idx += stride) {
        f32x4 v = s4[idx];
        uint2 o;
        o.x = f2bf(v.x) | (f2bf(v.y) << 16);
        o.y = f2bf(v.z) | (f2bf(v.w) << 16);
        ((uint2*)dst)[idx] = o;
    }
}

// ---------------- embed gather + xproj = emb @ W_ih^T + b_ih (fp32) ----------------
__global__ __launch_bounds__(256) void k_xproj(
        const int* __restrict__ inputs, const float* __restrict__ embed,
        const float* __restrict__ W_ih, const float* __restrict__ b_ih,
        float* __restrict__ xproj) {
    __shared__ float As[64][33];
    __shared__ float Bs[64][33];
    __shared__ int   idx_s[64];
    const int tid = threadIdx.x;
    const int bm = blockIdx.y, bn = blockIdx.x;
    if (tid < 64) {
        int m = bm * 64 + tid;
        idx_s[tid] = inputs[(m & 7) * T_SEQ + (m >> 3)];
    }
    __syncthreads();
    const int ty = tid >> 4, tx = tid & 15;
    const int lr = tid >> 2, lc = (tid & 3) * 8;
    float acc[4][4] = {};
    for (int kk = 0; kk < EMB; kk += 32) {
        __syncthreads();
        const float* arow = embed + (size_t)idx_s[lr] * EMB + kk + lc;
        f32x4 a0 = *(const f32x4*)arow;
        f32x4 a1 = *(const f32x4*)(arow + 4);
        const float* brow = W_ih + (size_t)(bn * 64 + lr) * EMB + kk + lc;
        f32x4 b0 = *(const f32x4*)brow;
        f32x4 b1 = *(const f32x4*)(brow + 4);
#pragma unroll
        for (int u = 0; u < 4; ++u) {
            As[lr][lc + u] = a0[u]; As[lr][lc + 4 + u] = a1[u];
            Bs[lr][lc + u] = b0[u]; Bs[lr][lc + 4 + u] = b1[u];
        }
        __syncthreads();
#pragma unroll
        for (int k = 0; k < 32; ++k) {
            float av[4], bv[4];
#pragma unroll
            for (int i = 0; i < 4; ++i) av[i] = As[ty * 4 + i][k];
#pragma unroll
            for (int j = 0; j < 4; ++j) bv[j] = Bs[tx * 4 + j][k];
#pragma unroll
            for (int i = 0; i < 4; ++i)
#pragma unroll
                for (int j = 0; j < 4; ++j) acc[i][j] += av[i] * bv[j];
        }
    }
#pragma unroll
    for (int i = 0; i < 4; ++i) {
        int m = bm * 64 + ty * 4 + i;
#pragma unroll
        for (int j = 0; j < 4; ++j) {
            int n = bn * 64 + tx * 4 + j;
            xproj[(size_t)m * HID + n] = acc[i][j] + b_ih[n];
        }
    }
}

// ---------------- persistent recurrence: 64 blocks x 256 threads, MFMA ----------------
// h published as packed u32 (bf16hi<<16 | bf16lo) in ring slot [8][1024]; sentinel
// poll = fragment load. Per block D[16x16] = h @ W_slice via split-bf16 3-MFMA
// (fp32-equivalent). Wave w handles K-quarter w; 8KB LDS joins partials.
#define RBLK 64
__global__ __launch_bounds__(256, 1) void k_rnn(
        const float* __restrict__ W_hh, const float* __restrict__ b_hh,
        const float* __restrict__ xproj,
        unsigned int* __restrict__ hpk /* [RING][8][1024] u32 */,
        unsigned short* __restrict__ hs /* [2048][1024] bf16 */) {
    __shared__ __align__(16) float part[2][4][64][4];   // 8 KB, dbuf by t&1
    const int tid = threadIdx.x;
    const int w   = tid >> 6;
    const int ln  = tid & 63;
    const int blk = blockIdx.x;

    // ---- preload W fragments (split hi/lo bf16), B-frag layout:
    // lane ln supplies W_hh[blk*16+(ln&15)][k0 + (ln>>4)*8 + j]
    const float* wrow = W_hh + (size_t)(blk * 16 + (ln & 15)) * HID;
    bf16x8 whi[8], wlo[8];
#pragma unroll
    for (int cc = 0; cc < 8; ++cc) {
        int k0 = w * 256 + cc * 32 + (ln >> 4) * 8;
        f32x4 wa = *(const f32x4*)(wrow + k0);
        f32x4 wb = *(const f32x4*)(wrow + k0 + 4);
        float wv[8] = { wa.x, wa.y, wa.z, wa.w, wb.x, wb.y, wb.z, wb.w };
        uint32_t hu[8], lu[8];
#pragma unroll
        for (int j = 0; j < 8; ++j) {
            hu[j] = f2bf(wv[j]);
            float hif = __builtin_bit_cast(float, hu[j] << 16);
            lu[j] = f2bf(wv[j] - hif);
        }
        u32x4 ph = { hu[0] | (hu[1] << 16), hu[2] | (hu[3] << 16),
                     hu[4] | (hu[5] << 16), hu[6] | (hu[7] << 16) };
        u32x4 pl = { lu[0] | (lu[1] << 16), lu[2] | (lu[3] << 16),
                     lu[4] | (lu[5] << 16), lu[6] | (lu[7] << 16) };
        whi[cc] = __builtin_bit_cast(bf16x8, ph);
        wlo[cc] = __builtin_bit_cast(bf16x8, pl);
    }

    const float bhh = b_hh[blk * 16 + (ln & 15)];
    // consumer poll base: rows 8-15 duplicate rows 0-7 (discarded C rows)
    const int frag_k = w * 256 + (ln >> 4) * 8;

    for (int t = 0; t < T_SEQ; ++t) {
        // xproj prefetch (wave 0): issued before the poll, consumed in epilogue
        float xp[4];
        if (w == 0) {
            int colp = blk * 16 + (ln & 15);
            int bb = (ln >> 4) * 4;
#pragma unroll
            for (int r = 0; r < 4; ++r) {
                int b = (bb + r) & 7;
                xp[r] = xproj[(size_t)(t * NB + b) * HID + colp];
            }
        }

        f32x4 acc0 = {0.f, 0.f, 0.f, 0.f}, acc1 = {0.f, 0.f, 0.f, 0.f};
        if (t > 0) {
            const unsigned int* hp = hpk + (size_t)((t - 1) & (RING - 1)) * 8192
                                         + (ln & 7) * 1024 + frag_k;
            u32x4 q0, q1, q2, q3, q4, q5, q6, q7, q8, q9, q10, q11, q12, q13, q14, q15;
            uint32_t bad;
            do {
                asm volatile(
                    "global_load_dwordx4 %0, %16, off sc0 sc1\n\t"
                    "global_load_dwordx4 %1, %16, off offset:16 sc0 sc1\n\t"
                    "global_load_dwordx4 %2, %16, off offset:128 sc0 sc1\n\t"
                    "global_load_dwordx4 %3, %16, off offset:144 sc0 sc1\n\t"
                    "global_load_dwordx4 %4, %16, off offset:256 sc0 sc1\n\t"
                    "global_load_dwordx4 %5, %16, off offset:272 sc0 sc1\n\t"
                    "global_load_dwordx4 %6, %16, off offset:384 sc0 sc1\n\t"
                    "global_load_dwordx4 %7, %16, off offset:400 sc0 sc1\n\t"
                    "global_load_dwordx4 %8, %16, off offset:512 sc0 sc1\n\t"
                    "global_load_dwordx4 %9, %16, off offset:528 sc0 sc1\n\t"
                    "global_load_dwordx4 %10, %16, off offset:640 sc0 sc1\n\t"
                    "global_load_dwordx4 %11, %16, off offset:656 sc0 sc1\n\t"
                    "global_load_dwordx4 %12, %16, off offset:768 sc0 sc1\n\t"
                    "global_load_dwordx4 %13, %16, off offset:784 sc0 sc1\n\t"
                    "global_load_dwordx4 %14, %16, off offset:896 sc0 sc1\n\t"
                    "global_load_dwordx4 %15, %16, off offset:912 sc0 sc1\n\t"
                    "s_waitcnt vmcnt(0)"
                    : "=&v"(q0), "=&v"(q1), "=&v"(q2), "=&v"(q3),
                      "=&v"(q4), "=&v"(q5), "=&v"(q6), "=&v"(q7),
                      "=&v"(q8), "=&v"(q9), "=&v"(q10), "=&v"(q11),
                      "=&v"(q12), "=&v"(q13), "=&v"(q14), "=&v"(q15)
                    : "v"(hp)
                    : "memory");
                bad = 0;
#define CKQ(q) bad |= (uint32_t)((q.x == SEN) | (q.y == SEN) | (q.z == SEN) | (q.w == SEN))
                CKQ(q0); CKQ(q1); CKQ(q2); CKQ(q3); CKQ(q4); CKQ(q5); CKQ(q6); CKQ(q7);
                CKQ(q8); CKQ(q9); CKQ(q10); CKQ(q11); CKQ(q12); CKQ(q13); CKQ(q14); CKQ(q15);
#undef CKQ
            } while (bad);

#define DO_CHUNK(qa, qb, WH, WL, ACC) do {                                          \
            bf16x8 ah = mk_hi(qa, qb);                                              \
            bf16x8 al = mk_lo(qa, qb);                                              \
            ACC = __builtin_amdgcn_mfma_f32_16x16x32_bf16(ah, WH, ACC, 0, 0, 0);    \
            ACC = __builtin_amdgcn_mfma_f32_16x16x32_bf16(al, WH, ACC, 0, 0, 0);    \
            ACC = __builtin_amdgcn_mfma_f32_16x16x32_bf16(ah, WL, ACC, 0, 0, 0);    \
        } while (0)
            DO_CHUNK(q0,  q1,  whi[0], wlo[0], acc0);
            DO_CHUNK(q2,  q3,  whi[1], wlo[1], acc1);
            DO_CHUNK(q4,  q5,  whi[2], wlo[2], acc0);
            DO_CHUNK(q6,  q7,  whi[3], wlo[3], acc1);
            DO_CHUNK(q8,  q9,  whi[4], wlo[4], acc0);
            DO_CHUNK(q10, q11, whi[5], wlo[5], acc1);
            DO_CHUNK(q12, q13, whi[6], wlo[6], acc0);
            DO_CHUNK(q14, q15, whi[7], wlo[7], acc1);
#undef DO_CHUNK
        }
        f32x4 asum = acc0 + acc1;
        *(f32x4*)&part[t & 1][w][ln][0] = asum;
        __syncthreads();

        if (w == 0) {
            f32x4 p0 = *(const f32x4*)&part[t & 1][0][ln][0];
            f32x4 p1 = *(const f32x4*)&part[t & 1][1][ln][0];
            f32x4 p2 = *(const f32x4*)&part[t & 1][2][ln][0];
            f32x4 p3 = *(const f32x4*)&part[t & 1][3][ln][0];
            f32x4 csum = (p0 + p1) + (p2 + p3);
            if (ln < 32) {
                // C/D layout: col = ln&15, rows (ln>>4)*4 + r = batch
                int colp = blk * 16 + (ln & 15);
                int bb = (ln >> 4) * 4;
                unsigned int* slot_w = hpk + (size_t)(t & (RING - 1)) * 8192;
                unsigned int* slot_s = hpk + (size_t)((t + RING - 3) & (RING - 1)) * 8192;
#pragma unroll
                for (int r = 0; r < 4; ++r) {
                    int b = bb + r;
                    float x = xp[r] + csum[r] + bhh;
                    float h = tanhf(x);
                    uint32_t hi = f2bf(h);
                    float hif = __builtin_bit_cast(float, hi << 16);
                    uint32_t lo = f2bf(h - hif);
                    uint32_t pk = (hi << 16) | lo;
                    unsigned int* ha = slot_w + b * 1024 + colp;
                    asm volatile("global_store_dword %0, %1, off sc0 sc1"
                                 :: "v"(ha), "v"(pk) : "memory");
                    hs[(size_t)(t * NB + b) * HID + colp] = (unsigned short)hi;
                    unsigned int* sa = slot_s + b * 1024 + colp;
                    unsigned int sv = SEN;
                    asm volatile("global_store_dword %0, %1, off sc0 sc1"
                                 :: "v"(sa), "v"(sv) : "memory");
                }
            }
        }
    }
}

// ---------------- fc: C[m][n] = hs[m][:] . W_fc[n][:] + b_fc[n], bf16 MFMA ----------------
__global__ void k_fc(const unsigned short* __restrict__ A,   // [2048][1024] bf16
                     const unsigned short* __restrict__ Bw,  // [32000][1024] bf16
                     const float* __restrict__ bias,
                     float* __restrict__ out) {              // [8][256][32000] f32
    __shared__ __align__(16) unsigned short As[128 * 32];
    __shared__ __align__(16) unsigned short Bs[128 * 32];
    const int tid = threadIdx.x;
    const int w = tid >> 6, ln = tid & 63;
    const int bm = blockIdx.x, bn = blockIdx.y;
    const int wm = (w >> 1) * 64, wn = (w & 1) * 64;
    const int srow = tid >> 2;
    const int scol = (tid & 3) * 8;
    const unsigned short* Ag = A  + (size_t)(bm * 128 + srow) * 1024 + scol;
    const unsigned short* Bg = Bw + (size_t)(bn * 128 + srow) * 1024 + scol;
    unsigned short* ldsA0 = As + w * 512;
    unsigned short* ldsA1 = As + 2048 + w * 512;
    unsigned short* ldsB0 = Bs + w * 512;
    unsigned short* ldsB1 = Bs + 2048 + w * 512;

    f32x4 acc[4][4] = {};
    const int fr = ln & 15;
    const int kq = (ln >> 4) * 8;

    for (int kk = 0; kk < 1024; kk += 32) {
        __syncthreads();
        __builtin_amdgcn_global_load_lds((const AS1 void*)(Ag + kk),             (AS3 void*)ldsA0, 16, 0, 0);
        __builtin_amdgcn_global_load_lds((const AS1 void*)(Ag + 64 * 1024 + kk), (AS3 void*)ldsA1, 16, 0, 0);
        __builtin_amdgcn_global_load_lds((const AS1 void*)(Bg + kk),             (AS3 void*)ldsB0, 16, 0, 0);
        __builtin_amdgcn_global_load_lds((const AS1 void*)(Bg + 64 * 1024 + kk), (AS3 void*)ldsB1, 16, 0, 0);
        __syncthreads();
        bf16x8 af[4], bf[4];
#pragma unroll
        for (int i = 0; i < 4; ++i)
            af[i] = *(const bf16x8*)&As[(wm + i * 16 + fr) * 32 + kq];
#pragma unroll
        for (int j = 0; j < 4; ++j)
            bf[j] = *(const bf16x8*)&Bs[(wn + j * 16 + fr) * 32 + kq];
#pragma unroll
        for (int i = 0; i < 4; ++i)
#pragma unroll
            for (int j = 0; j < 4; ++j)
                acc[i][j] = __builtin_amdgcn_mfma_f32_16x16x32_bf16(af[i], bf[j], acc[i][j], 0, 0, 0);
    }

    const int fq = ln >> 4;
#pragma unroll
    for (int i = 0; i < 4; ++i) {
#pragma unroll
        for (int j = 0; j < 4; ++j) {
            int n = bn * 128 + wn + j * 16 + fr;
            float bv = bias[n];
#pragma unroll
            for (int r = 0; r < 4; ++r) {
                int m = bm * 128 + wm + i * 16 + fq * 4 + r;
                int t = m >> 3, b = m & 7;
                out[(size_t)b * T_SEQ * NOUT + (size_t)t * NOUT + n] = acc[i][j][r] + bv;
            }
        }
    }
}

extern "C" void kernel_launch(void* const* d_in, const int* in_sizes, int n_in,
                              void* d_out, int out_size, void* d_ws, size_t ws_size,
                              hipStream_t stream) {
    const int*   inputs = (const int*)d_in[0];
    const float* embed  = (const float*)d_in[1];
    const float* W_ih   = (const float*)d_in[2];
    const float* W_hh   = (const float*)d_in[3];
    const float* b_ih   = (const float*)d_in[4];
    const float* b_hh   = (const float*)d_in[5];
    const float* W_fc   = (const float*)d_in[6];
    const float* b_fc   = (const float*)d_in[7];
    float* out = (float*)d_out;

    char* ws = (char*)d_ws;
    unsigned int*   hpk   = (unsigned int*)(ws);                        // RING*8*1024*4 = 512 KB
    float*          xproj = (float*)(ws + 524288);                      // 2048*1024*4 = 8 MB
    unsigned short* hs    = (unsigned short*)(ws + 524288 + 8388608);   // 4 MB
    unsigned short* wfcb  = (unsigned short*)(ws + 524288 + 8388608 + 4194304); // 64 MB

    k_fill<<<128, 256, 0, stream>>>(hpk);
    k_convert_wfc<<<2048, 256, 0, stream>>>(W_fc, wfcb);
    k_xproj<<<dim3(16, 32), 256, 0, stream>>>(inputs, embed, W_ih, b_ih, xproj);
    k_rnn<<<RBLK, 256, 0, stream>>>(W_hh, b_hh, xproj, hpk, hs);
    k_fc<<<dim3(16, 250), 256, 0, stream>>>(hs, wfcb, b_fc, out);
}